// Round 5
// baseline (254.904 us; speedup 1.0000x reference)
//
#include <hip/hip_runtime.h>
#include <math.h>

#define TPB  256
#define TILE 512     // tokens per block (2 per thread)
#define GRAN 64      // boundary granularity = wave window

// K1: boundary[b] = lower_bound(pu, 64*b), computed by inversion (no search).
__global__ __launch_bounds__(TPB) void boundary_kernel(
    const int* __restrict__ pu, int P, int NB, int* __restrict__ boundary)
{
    int i = blockIdx.x * TPB + threadIdx.x;
    if (i >= P) return;
    int cur = pu[i];
    int lo  = (i == 0) ? 0 : (pu[i - 1] / GRAN) + 1;
    int hi  = cur / GRAN;                      // inclusive
    for (int bb = lo; bb <= hi; ++bb) boundary[bb] = i;
    if (i == P - 1)
        for (int bb = hi + 1; bb <= NB; ++bb) boundary[bb] = P;
}

// K2: fused verblizer — ZERO barriers, ZERO LDS. Each wave autonomously owns
// 128 tokens (two 64-token windows). pu membership/rank via register-only
// butterfly-OR bitmask; argmax entirely in-registers (thread owns its tokens'
// x data); W/b gathered from global (L1-resident, 480 B).
__global__ __launch_bounds__(TPB) void verblizer_fused_kernel(
    const float4* __restrict__ x4,   // [S*5] float4 view of x[1,S,20]
    const float2* __restrict__ h2,   // [S]
    const float*  __restrict__ W,    // [20,2,2]
    const float*  __restrict__ b,    // [20,2]
    const int*    __restrict__ pu,   // [P] sorted unique
    const int*    __restrict__ boundary, // [NB+1]
    float2*       __restrict__ y,    // out1 [S]
    float2*       __restrict__ y2,   // out2 [S]
    int S, int P)
{
    const int t    = threadIdx.x;
    const int lane = t & 63;
    const int w    = t >> 6;
    const int B0   = min((int)blockIdx.x * TILE, S - TILE);  // full blocks only;
    // overlapping blocks write identical values -> benign

    const int base = B0 + 128 * w;          // wave owns [base, base+128)
    const int s0   = base + lane;
    const int s1   = base + 64 + lane;

    // ---- issue ALL loads before any use ----
    const int wi  = __builtin_amdgcn_readfirstlane(base >> 6);
    const int rA0 = boundary[wi];
    const int rA1 = boundary[wi + 1];
    const int rB1 = boundary[wi + 2];

    const int pA = pu[min(rA0 + lane, P - 1)];
    const int pB = pu[min(rA1 + lane, P - 1)];

    float4 xa[5], xbv[5];
    const float4* xp0 = x4 + (size_t)s0 * 5;
    const float4* xp1 = x4 + (size_t)s1 * 5;
#pragma unroll
    for (int c = 0; c < 5; ++c) { xa[c] = xp0[c]; xbv[c] = xp1[c]; }
    const float2 h0 = h2[s0];
    const float2 h1 = h2[s1];

    // ---- wave-window membership masks (register-only butterfly OR) ----
    const int nA = rA1 - rA0;
    const int nB = rB1 - rA1;
    unsigned long long mA = (lane < nA) ? (1ull << ((unsigned)(pA - base) & 63)) : 0ull;
    unsigned long long mB = (lane < nB) ? (1ull << ((unsigned)(pB - base - 64) & 63)) : 0ull;
#pragma unroll
    for (int d = 1; d < 64; d <<= 1) {
        mA |= __shfl_xor(mA, d, 64);
        mB |= __shfl_xor(mB, d, 64);
    }
    const unsigned long long lt = (1ull << lane) - 1ull;
    const int  rankA = rA0 + __popcll(mA & lt);
    const int  rankB = rA1 + __popcll(mB & lt);
    const bool fA    = (mA >> lane) & 1;
    const bool fB    = (mB >> lane) & 1;

    // ---- per-token epilogue (all in registers) ----
#pragma unroll
    for (int half = 0; half < 2; ++half) {
        const float4* xv  = half ? xbv : xa;
        const float2  hv  = half ? h1 : h0;
        const int     s   = half ? s1 : s0;
        const bool    f   = half ? fB : fA;
        const int     rnk = half ? rankB : rankA;

        float best = -INFINITY; int bi = 0;
#pragma unroll
        for (int c = 0; c < 5; ++c) {
            float4 v = xv[c];
            if (v.x > best) { best = v.x; bi = 4 * c + 0; }
            if (v.y > best) { best = v.y; bi = 4 * c + 1; }
            if (v.z > best) { best = v.z; bi = 4 * c + 2; }
            if (v.w > best) { best = v.w; bi = 4 * c + 3; }
        }

        const float4 wv = *(const float4*)(W + bi * 4);  // L1-resident gather
        const float2 bv = *(const float2*)(b + bi * 2);
        float y0 = fmaf(hv.x, wv.x, fmaf(hv.y, wv.y, bv.x));
        float y1 = fmaf(hv.x, wv.z, fmaf(hv.y, wv.w, bv.y));
        float mx = fmaxf(y0, y1);
        float e0 = __expf(y0 - mx);
        float e1 = __expf(y1 - mx);
        float inv = 1.0f / (e0 + e1);
        float2 yo = make_float2(e0 * inv, e1 * inv);

        y[s] = yo;
        const int dst = f ? rnk : (P + s - rnk);
        y2[dst] = yo;
    }
}

extern "C" void kernel_launch(void* const* d_in, const int* in_sizes, int n_in,
                              void* d_out, int out_size, void* d_ws, size_t ws_size,
                              hipStream_t stream) {
    const float* x  = (const float*)d_in[0];   // [1,S,20]
    const float* h  = (const float*)d_in[1];   // [S,2]
    const float* W  = (const float*)d_in[2];   // [20,2,2]
    const float* b  = (const float*)d_in[3];   // [20,2]
    const int*   pu = (const int*)d_in[4];     // [P]

    const int S  = in_sizes[1] / 2;
    const int P  = in_sizes[4];
    const int NB = S / GRAN;                   // S divisible by 64

    int* boundary = (int*)d_ws;                // NB+1 ints

    float2* y  = (float2*)d_out;
    float2* y2 = (float2*)d_out + S;

    boundary_kernel<<<(P + TPB - 1) / TPB, TPB, 0, stream>>>(pu, P, NB, boundary);

    const int grid = (S + TILE - 1) / TILE;
    verblizer_fused_kernel<<<grid, TPB, 0, stream>>>(
        (const float4*)x, (const float2*)h, W, b, pu, boundary, y, y2, S, P);
}

// Round 6
// 251.729 us; speedup vs baseline: 1.0126x; 1.0126x over previous
//
#include <hip/hip_runtime.h>
#include <math.h>

#define TPB  256
#define GRAN 64      // boundary granularity = wave window

// K1: boundary[b] = lower_bound(pu, 64*b), computed by inversion (no search).
__global__ __launch_bounds__(TPB) void boundary_kernel(
    const int* __restrict__ pu, int P, int NB, int* __restrict__ boundary)
{
    int i = blockIdx.x * TPB + threadIdx.x;
    if (i >= P) return;
    int cur = pu[i];
    int lo  = (i == 0) ? 0 : (pu[i - 1] / GRAN) + 1;
    int hi  = cur / GRAN;                      // inclusive
    for (int bb = lo; bb <= hi; ++bb) boundary[bb] = i;
    if (i == P - 1)
        for (int bb = hi + 1; bb <= NB; ++bb) boundary[bb] = P;
}

// K2: fused verblizer — zero barriers, COALESCED x loads, wave-private LDS
// scratch for the chunk-candidate transpose (same-wave dep -> lgkmcnt only,
// no __syncthreads). Wave autonomously owns 64 tokens.
__global__ __launch_bounds__(TPB) void verblizer_fused_kernel(
    const float4* __restrict__ x4,   // [S*5] float4 view of x[1,S,20]
    const float2* __restrict__ h2,   // [S]
    const float*  __restrict__ W,    // [20,2,2]
    const float*  __restrict__ b,    // [20,2]
    const int*    __restrict__ pu,   // [P] sorted unique
    const int*    __restrict__ boundary, // [NB+1]
    float2*       __restrict__ y,    // out1 [S]
    float2*       __restrict__ y2,   // out2 [S]
    int S, int P)
{
    __shared__ uint2 scratch[(TPB / 64) * 320];  // wave-private, 10 KB/block

    const int t    = threadIdx.x;
    const int lane = t & 63;
    const int w    = t >> 6;
    const int B0   = min((int)blockIdx.x * TPB, S - TPB);  // full blocks only;
    // overlapping blocks write identical values -> benign. B0 is 64-aligned.

    const int base = B0 + 64 * w;          // wave owns [base, base+64)
    const int s    = base + lane;

    // ---- issue ALL global loads before any use ----
    const int wi = __builtin_amdgcn_readfirstlane(base >> 6);
    const int r0 = boundary[wi];
    const int r1 = boundary[wi + 1];

    float4 xv[5];
    const float4* xp = x4 + (size_t)base * 5;   // 320 contiguous float4s
#pragma unroll
    for (int j = 0; j < 5; ++j) xv[j] = xp[64 * j + lane];   // coalesced

    const float2 hv = h2[s];
    const int    pv = pu[min(r0 + lane, P - 1)];

    // ---- wave-window membership mask (register-only butterfly OR) ----
    const int nmark = r1 - r0;
    unsigned long long m =
        (lane < nmark) ? (1ull << ((unsigned)(pv - base) & 63)) : 0ull;
#pragma unroll
    for (int d = 1; d < 64; d <<= 1) m |= __shfl_xor(m, d, 64);
    const int  rank = r0 + __popcll(m & ((1ull << lane) - 1ull));
    const bool f    = (m >> lane) & 1;

    // ---- per-chunk candidates -> wave-private LDS (no barrier) ----
    uint2* sw = scratch + w * 320;
#pragma unroll
    for (int j = 0; j < 5; ++j) {
        float4 v = xv[j];
        float best = v.x; int bi = 0;
        if (v.y > best) { best = v.y; bi = 1; }
        if (v.z > best) { best = v.z; bi = 2; }
        if (v.w > best) { best = v.w; bi = 3; }
        const int flat = 64 * j + lane;     // chunk index in wave's span
        const int c    = flat % 5;          // chunk class within its token
        sw[flat] = make_uint2(__float_as_uint(best), (unsigned)(4 * c + bi));
    }
    // compiler inserts lgkmcnt wait for same-wave LDS dependency

    // ---- combine own token's 5 candidates (ascending c = first-max) ----
    float best = -INFINITY; int bi = 0;
#pragma unroll
    for (int c = 0; c < 5; ++c) {
        uint2 p = sw[5 * lane + c];
        float v = __uint_as_float(p.x);
        if (v > best) { best = v; bi = (int)p.y; }
    }

    // ---- Linear(2,2) + softmax(2); W/b gathered from global (L1-resident) ----
    const float4 wv = *(const float4*)(W + bi * 4);
    const float2 bv = *(const float2*)(b + bi * 2);
    float y0 = fmaf(hv.x, wv.x, fmaf(hv.y, wv.y, bv.x));
    float y1 = fmaf(hv.x, wv.z, fmaf(hv.y, wv.w, bv.y));
    float mx = fmaxf(y0, y1);
    float e0 = __expf(y0 - mx);
    float e1 = __expf(y1 - mx);
    float inv = 1.0f / (e0 + e1);
    float2 yo = make_float2(e0 * inv, e1 * inv);

    y[s] = yo;
    const int dst = f ? rank : (P + s - rank);
    y2[dst] = yo;
}

extern "C" void kernel_launch(void* const* d_in, const int* in_sizes, int n_in,
                              void* d_out, int out_size, void* d_ws, size_t ws_size,
                              hipStream_t stream) {
    const float* x  = (const float*)d_in[0];   // [1,S,20]
    const float* h  = (const float*)d_in[1];   // [S,2]
    const float* W  = (const float*)d_in[2];   // [20,2,2]
    const float* b  = (const float*)d_in[3];   // [20,2]
    const int*   pu = (const int*)d_in[4];     // [P]

    const int S  = in_sizes[1] / 2;
    const int P  = in_sizes[4];
    const int NB = S / GRAN;                   // S divisible by 64

    int* boundary = (int*)d_ws;                // NB+1 ints

    float2* y  = (float2*)d_out;
    float2* y2 = (float2*)d_out + S;

    boundary_kernel<<<(P + TPB - 1) / TPB, TPB, 0, stream>>>(pu, P, NB, boundary);

    const int grid = (S + TPB - 1) / TPB;      // overlap-clamped full blocks
    verblizer_fused_kernel<<<grid, TPB, 0, stream>>>(
        (const float4*)x, (const float2*)h, W, b, pu, boundary, y, y2, S, P);
}

// Round 8
// 239.137 us; speedup vs baseline: 1.0659x; 1.0527x over previous
//
#include <hip/hip_runtime.h>
#include <math.h>

#define TPB  256
#define GRAN 64      // boundary granularity = wave window

typedef float v4f __attribute__((ext_vector_type(4)));
typedef float v2f __attribute__((ext_vector_type(2)));

// K1: boundary[b] = lower_bound(pu, 64*b), computed by inversion (no search).
__global__ __launch_bounds__(TPB) void boundary_kernel(
    const int* __restrict__ pu, int P, int NB, int* __restrict__ boundary)
{
    int i = blockIdx.x * TPB + threadIdx.x;
    if (i >= P) return;
    int cur = pu[i];
    int lo  = (i == 0) ? 0 : (pu[i - 1] / GRAN) + 1;
    int hi  = cur / GRAN;                      // inclusive
    for (int bb = lo; bb <= hi; ++bb) boundary[bb] = i;
    if (i == P - 1)
        for (int bb = hi + 1; bb <= NB; ++bb) boundary[bb] = P;
}

// K2: identical structure to R6 (zero barriers, coalesced x, wave-private LDS
// scratch) but one-pass streams use nontemporal cache policy via native
// ext_vector types:
//   loads:  x (160 MB), h (16 MB)   -> minimize cache install/writeback war
//   stores: y, y2 (32 MB)           -> no write-allocate
// W/b/pu/boundary stay cached (reused across waves).
__global__ __launch_bounds__(TPB) void verblizer_fused_kernel(
    const v4f*  __restrict__ x4,     // [S*5] float4 view of x[1,S,20]
    const v2f*  __restrict__ h2,     // [S]
    const float* __restrict__ W,     // [20,2,2]
    const float* __restrict__ b,     // [20,2]
    const int*   __restrict__ pu,    // [P] sorted unique
    const int*   __restrict__ boundary, // [NB+1]
    v2f*         __restrict__ y,     // out1 [S]
    v2f*         __restrict__ y2,    // out2 [S]
    int S, int P)
{
    __shared__ uint2 scratch[(TPB / 64) * 320];  // wave-private, 10 KB/block

    const int t    = threadIdx.x;
    const int lane = t & 63;
    const int w    = t >> 6;
    const int B0   = min((int)blockIdx.x * TPB, S - TPB);  // full blocks only
    // overlapping blocks write identical values -> benign. B0 is 64-aligned.

    const int base = B0 + 64 * w;          // wave owns [base, base+64)
    const int s    = base + lane;

    // ---- issue ALL global loads before any use ----
    const int wi = __builtin_amdgcn_readfirstlane(base >> 6);
    const int r0 = boundary[wi];
    const int r1 = boundary[wi + 1];

    v4f xv[5];
    const v4f* xp = x4 + (size_t)base * 5;      // 320 contiguous float4s
#pragma unroll
    for (int j = 0; j < 5; ++j)
        xv[j] = __builtin_nontemporal_load(xp + 64 * j + lane);   // coalesced, nt

    const v2f hv = __builtin_nontemporal_load(h2 + s);
    const int pv = pu[min(r0 + lane, P - 1)];

    // ---- wave-window membership mask (register-only butterfly OR) ----
    const int nmark = r1 - r0;
    unsigned long long m =
        (lane < nmark) ? (1ull << ((unsigned)(pv - base) & 63)) : 0ull;
#pragma unroll
    for (int d = 1; d < 64; d <<= 1) m |= __shfl_xor(m, d, 64);
    const int  rank = r0 + __popcll(m & ((1ull << lane) - 1ull));
    const bool f    = (m >> lane) & 1;

    // ---- per-chunk candidates -> wave-private LDS (no barrier) ----
    uint2* sw = scratch + w * 320;
#pragma unroll
    for (int j = 0; j < 5; ++j) {
        v4f v = xv[j];
        float best = v.x; int bi = 0;
        if (v.y > best) { best = v.y; bi = 1; }
        if (v.z > best) { best = v.z; bi = 2; }
        if (v.w > best) { best = v.w; bi = 3; }
        const int flat = 64 * j + lane;     // chunk index in wave's span
        const int c    = flat % 5;          // chunk class within its token
        sw[flat] = make_uint2(__float_as_uint(best), (unsigned)(4 * c + bi));
    }
    // compiler inserts lgkmcnt wait for same-wave LDS dependency

    // ---- combine own token's 5 candidates (ascending c = first-max) ----
    float best = -INFINITY; int bi = 0;
#pragma unroll
    for (int c = 0; c < 5; ++c) {
        uint2 p = sw[5 * lane + c];
        float v = __uint_as_float(p.x);
        if (v > best) { best = v; bi = (int)p.y; }
    }

    // ---- Linear(2,2) + softmax(2); W/b gathered from global (L1-resident) ----
    const float4 wv = *(const float4*)(W + bi * 4);
    const float2 bv = *(const float2*)(b + bi * 2);
    float y0 = fmaf(hv.x, wv.x, fmaf(hv.y, wv.y, bv.x));
    float y1 = fmaf(hv.x, wv.z, fmaf(hv.y, wv.w, bv.y));
    float mx = fmaxf(y0, y1);
    float e0 = __expf(y0 - mx);
    float e1 = __expf(y1 - mx);
    float inv = 1.0f / (e0 + e1);
    v2f yo = { e0 * inv, e1 * inv };

    __builtin_nontemporal_store(yo, y + s);
    const int dst = f ? rank : (P + s - rank);
    __builtin_nontemporal_store(yo, y2 + dst);
}

extern "C" void kernel_launch(void* const* d_in, const int* in_sizes, int n_in,
                              void* d_out, int out_size, void* d_ws, size_t ws_size,
                              hipStream_t stream) {
    const float* x  = (const float*)d_in[0];   // [1,S,20]
    const float* h  = (const float*)d_in[1];   // [S,2]
    const float* W  = (const float*)d_in[2];   // [20,2,2]
    const float* b  = (const float*)d_in[3];   // [20,2]
    const int*   pu = (const int*)d_in[4];     // [P]

    const int S  = in_sizes[1] / 2;
    const int P  = in_sizes[4];
    const int NB = S / GRAN;                   // S divisible by 64

    int* boundary = (int*)d_ws;                // NB+1 ints

    v2f* y  = (v2f*)d_out;
    v2f* y2 = (v2f*)d_out + S;

    boundary_kernel<<<(P + TPB - 1) / TPB, TPB, 0, stream>>>(pu, P, NB, boundary);

    const int grid = (S + TPB - 1) / TPB;      // overlap-clamped full blocks
    verblizer_fused_kernel<<<grid, TPB, 0, stream>>>(
        (const v4f*)x, (const v2f*)h, W, b, pu, boundary, y, y2, S, P);
}

// Round 9
// 238.883 us; speedup vs baseline: 1.0671x; 1.0011x over previous
//
#include <hip/hip_runtime.h>
#include <math.h>

#define TPB  256
#define TILE 512     // tokens per block; wave owns 128 (2/thread)
#define GRAN 64      // boundary granularity = wave window

typedef float v4f __attribute__((ext_vector_type(4)));
typedef float v2f __attribute__((ext_vector_type(2)));

// K1: boundary[b] = lower_bound(pu, 64*b), computed by inversion (no search).
__global__ __launch_bounds__(TPB) void boundary_kernel(
    const int* __restrict__ pu, int P, int NB, int* __restrict__ boundary)
{
    int i = blockIdx.x * TPB + threadIdx.x;
    if (i >= P) return;
    int cur = pu[i];
    int lo  = (i == 0) ? 0 : (pu[i - 1] / GRAN) + 1;
    int hi  = cur / GRAN;                      // inclusive
    for (int bb = lo; bb <= hi; ++bb) boundary[bb] = i;
    if (i == P - 1)
        for (int bb = hi + 1; bb <= NB; ++bb) boundary[bb] = P;
}

// K2: R8 structure (zero barriers, coalesced NT loads, wave-private LDS
// transpose, NT stores) with 2 tokens/thread: wave owns 128 tokens, issues
// 10 x-loads + 2 h-loads + 2 pu-loads back-to-back -> ~2x outstanding bytes.
__global__ __launch_bounds__(TPB) void verblizer_fused_kernel(
    const v4f*  __restrict__ x4,     // [S*5] float4 view of x[1,S,20]
    const v2f*  __restrict__ h2,     // [S]
    const float* __restrict__ W,     // [20,2,2]
    const float* __restrict__ b,     // [20,2]
    const int*   __restrict__ pu,    // [P] sorted unique
    const int*   __restrict__ boundary, // [NB+1]
    v2f*         __restrict__ y,     // out1 [S]
    v2f*         __restrict__ y2,    // out2 [S]
    int S, int P)
{
    __shared__ uint2 scratch[(TPB / 64) * 640];  // wave-private, 20 KB/block

    const int t    = threadIdx.x;
    const int lane = t & 63;
    const int w    = t >> 6;
    const int B0   = min((int)blockIdx.x * TILE, S - TILE);  // full blocks only
    // overlapping blocks write identical values -> benign. B0 is 64-aligned.

    const int base = B0 + 128 * w;         // wave owns [base, base+128)
    const int s0   = base + lane;
    const int s1   = base + 64 + lane;

    // ---- issue ALL global loads before any use ----
    const int wi = __builtin_amdgcn_readfirstlane(base >> 6);
    const int r0 = boundary[wi];
    const int r1 = boundary[wi + 1];
    const int r2 = boundary[wi + 2];

    v4f xv[10];
    const v4f* xp = x4 + (size_t)base * 5;      // 640 contiguous float4s
#pragma unroll
    for (int j = 0; j < 10; ++j)
        xv[j] = __builtin_nontemporal_load(xp + 64 * j + lane);   // coalesced, nt

    const v2f h0 = __builtin_nontemporal_load(h2 + s0);
    const v2f h1 = __builtin_nontemporal_load(h2 + s1);
    const int pA = pu[min(r0 + lane, P - 1)];
    const int pB = pu[min(r1 + lane, P - 1)];

    // ---- two wave-window membership masks (register-only butterfly OR) ----
    const int nA = r1 - r0;
    const int nB = r2 - r1;
    unsigned long long mA = (lane < nA) ? (1ull << ((unsigned)(pA - base) & 63)) : 0ull;
    unsigned long long mB = (lane < nB) ? (1ull << ((unsigned)(pB - base - 64) & 63)) : 0ull;
#pragma unroll
    for (int d = 1; d < 64; d <<= 1) {
        mA |= __shfl_xor(mA, d, 64);
        mB |= __shfl_xor(mB, d, 64);
    }
    const unsigned long long lt = (1ull << lane) - 1ull;
    const int  rankA = r0 + __popcll(mA & lt);
    const int  rankB = r1 + __popcll(mB & lt);
    const bool fA    = (mA >> lane) & 1;
    const bool fB    = (mB >> lane) & 1;

    // ---- per-chunk candidates -> wave-private LDS (no barrier) ----
    uint2* sw = scratch + w * 640;
#pragma unroll
    for (int j = 0; j < 10; ++j) {
        v4f v = xv[j];
        float best = v.x; int bi = 0;
        if (v.y > best) { best = v.y; bi = 1; }
        if (v.z > best) { best = v.z; bi = 2; }
        if (v.w > best) { best = v.w; bi = 3; }
        const int flat = 64 * j + lane;     // chunk index in wave's 128-token span
        const int c    = flat % 5;          // chunk class within its token
        sw[flat] = make_uint2(__float_as_uint(best), (unsigned)(4 * c + bi));
    }
    // compiler inserts lgkmcnt wait for same-wave LDS dependency

    // ---- per-token epilogue x2 ----
#pragma unroll
    for (int half = 0; half < 2; ++half) {
        const int   tl   = half ? (64 + lane) : lane;
        const v2f   hv   = half ? h1 : h0;
        const int   s    = half ? s1 : s0;
        const bool  f    = half ? fB : fA;
        const int   rnk  = half ? rankB : rankA;

        float best = -INFINITY; int bi = 0;
#pragma unroll
        for (int c = 0; c < 5; ++c) {
            uint2 p = sw[5 * tl + c];
            float v = __uint_as_float(p.x);
            if (v > best) { best = v; bi = (int)p.y; }
        }

        const float4 wv = *(const float4*)(W + bi * 4);  // L1-resident
        const float2 bv = *(const float2*)(b + bi * 2);
        float y0 = fmaf(hv.x, wv.x, fmaf(hv.y, wv.y, bv.x));
        float y1 = fmaf(hv.x, wv.z, fmaf(hv.y, wv.w, bv.y));
        float mx = fmaxf(y0, y1);
        float e0 = __expf(y0 - mx);
        float e1 = __expf(y1 - mx);
        float inv = 1.0f / (e0 + e1);
        v2f yo = { e0 * inv, e1 * inv };

        __builtin_nontemporal_store(yo, y + s);
        const int dst = f ? rnk : (P + s - rnk);
        __builtin_nontemporal_store(yo, y2 + dst);
    }
}

extern "C" void kernel_launch(void* const* d_in, const int* in_sizes, int n_in,
                              void* d_out, int out_size, void* d_ws, size_t ws_size,
                              hipStream_t stream) {
    const float* x  = (const float*)d_in[0];   // [1,S,20]
    const float* h  = (const float*)d_in[1];   // [S,2]
    const float* W  = (const float*)d_in[2];   // [20,2,2]
    const float* b  = (const float*)d_in[3];   // [20,2]
    const int*   pu = (const int*)d_in[4];     // [P]

    const int S  = in_sizes[1] / 2;
    const int P  = in_sizes[4];
    const int NB = S / GRAN;                   // S divisible by 64

    int* boundary = (int*)d_ws;                // NB+1 ints

    v2f* y  = (v2f*)d_out;
    v2f* y2 = (v2f*)d_out + S;

    boundary_kernel<<<(P + TPB - 1) / TPB, TPB, 0, stream>>>(pu, P, NB, boundary);

    const int grid = (S + TILE - 1) / TILE;    // overlap-clamped full blocks
    verblizer_fused_kernel<<<grid, TPB, 0, stream>>>(
        (const v4f*)x, (const v2f*)h, W, b, pu, boundary, y, y2, S, P);
}